// Round 1
// baseline (252.012 us; speedup 1.0000x reference)
//
#include <hip/hip_runtime.h>

// RGCN: out = relu( sum_r A_r @ (X W_r) + X Sk + bias )
// N=8192, F=U=64, R=4, B=20.  A (4,8192,8192) fp32 = 1.07 GB -> HBM-bound.

typedef float v4f __attribute__((ext_vector_type(4)));
typedef unsigned int v4u __attribute__((ext_vector_type(4)));
typedef short v8s __attribute__((ext_vector_type(8)));

__device__ __forceinline__ unsigned short f2bf(float f) {
  // round-to-nearest-even f32 -> bf16
  unsigned int u = __builtin_bit_cast(unsigned int, f);
  return (unsigned short)((u + 0x7fffu + ((u >> 16) & 1u)) >> 16);
}

// ---------------- kernel 0: W[r][f][u] = sum_k bases[f][u][k] * coef[r][k] ----
__global__ __launch_bounds__(256) void rgcn_wk(const float* __restrict__ bases,
                                               const float* __restrict__ coef,
                                               float* __restrict__ W) {
  int i = blockIdx.x * 256 + threadIdx.x;  // 64*256 = 16384 = R*F*U
  int r = i >> 12;
  int fu = i & 4095;
  float s = 0.f;
#pragma unroll
  for (int k = 0; k < 20; ++k) s += bases[fu * 20 + k] * coef[r * 20 + k];
  W[i] = s;
}

// ---------------- kernel 1: xw (bf16, swizzled to B-fragment layout) + selfout
// xwf layout: for K-step (r, m0=32*mb) and u-tile ut, lane l, elem j holds
//   xw[r][m0 + 8*(l>>4) + j][ut*16 + (l&15)]
//   at index ((r*256 + mb)*4 + ut)*512 + l*8 + j
__global__ __launch_bounds__(256) void rgcn_prep(const float* __restrict__ x,
                                                 const float* __restrict__ W,
                                                 const float* __restrict__ sk,
                                                 const float* __restrict__ bias,
                                                 unsigned short* __restrict__ xwf,
                                                 float* __restrict__ selfout) {
  __shared__ float lx[2048];            // 32 rows x 64 f
  __shared__ unsigned short lxw[8192];  // 4 rel x 2048 swizzled bf16
  const int t = threadIdx.x;
  const int blk = blockIdx.x;
  const int n0 = blk * 32;
  for (int i = t; i < 2048; i += 256) lx[i] = x[(size_t)n0 * 64 + i];
  __syncthreads();
  const int u = t & 63, rq = t >> 6;  // each thread: column u, rows rq*8..rq*8+7
  float acc[8][5];
#pragma unroll
  for (int p = 0; p < 8; ++p)
#pragma unroll
    for (int c = 0; c < 5; ++c) acc[p][c] = 0.f;
  const float* wu = W + u;   // W[r][f][u] = wu[r*4096 + f*64]
  const float* sku = sk + u;
#pragma unroll 4
  for (int f = 0; f < 64; ++f) {
    float w0 = wu[f * 64];
    float w1 = wu[4096 + f * 64];
    float w2 = wu[8192 + f * 64];
    float w3 = wu[12288 + f * 64];
    float w4 = sku[f * 64];
#pragma unroll
    for (int p = 0; p < 8; ++p) {
      float xv = lx[(rq * 8 + p) * 64 + f];
      acc[p][0] += xv * w0;
      acc[p][1] += xv * w1;
      acc[p][2] += xv * w2;
      acc[p][3] += xv * w3;
      acc[p][4] += xv * w4;
    }
  }
  const float bu = bias[u];
#pragma unroll
  for (int p = 0; p < 8; ++p) {
    int km = rq * 8 + p;  // local m index 0..31
    selfout[(size_t)(n0 + km) * 64 + u] = acc[p][4] + bu;
    int idx = (u >> 4) * 512 + ((km >> 3) * 16 + (u & 15)) * 8 + (km & 7);
#pragma unroll
    for (int r = 0; r < 4; ++r) lxw[r * 2048 + idx] = f2bf(acc[p][r]);
  }
  __syncthreads();
  const unsigned int* lsrc = (const unsigned int*)lxw;
  unsigned int* gdst = (unsigned int*)xwf;
  for (int i = t; i < 4096; i += 256) {  // 4 rel x 1024 dwords, coalesced
    int r = i >> 10, q = i & 1023;
    gdst[(size_t)(r * 256 + blk) * 1024 + q] = lsrc[i];
  }
}

// ---------------- kernel 2: out = relu( sum_r A_r @ xw_r + selfout ) --------
#define LD_STEP(it, A00, A01, A10, A11, B0, B1, B2, B3)      \
  {                                                          \
    const float* pa0 = a0 + (size_t)(it) * 32;               \
    const float* pa1 = a1 + (size_t)(it) * 32;               \
    A00 = *(const v4f*)(pa0);                                \
    A01 = *(const v4f*)(pa0 + 4);                            \
    A10 = *(const v4f*)(pa1);                                \
    A11 = *(const v4f*)(pa1 + 4);                            \
    const unsigned short* pb = b0 + (size_t)(it) * 2048;     \
    B0 = *(const v4u*)(pb);                                  \
    B1 = *(const v4u*)(pb + 512);                            \
    B2 = *(const v4u*)(pb + 1024);                           \
    B3 = *(const v4u*)(pb + 1536);                           \
  }

#define PACK8(S, X0, X1)                                     \
  {                                                          \
    S[0] = (short)f2bf(X0.x);                                \
    S[1] = (short)f2bf(X0.y);                                \
    S[2] = (short)f2bf(X0.z);                                \
    S[3] = (short)f2bf(X0.w);                                \
    S[4] = (short)f2bf(X1.x);                                \
    S[5] = (short)f2bf(X1.y);                                \
    S[6] = (short)f2bf(X1.z);                                \
    S[7] = (short)f2bf(X1.w);                                \
  }

#define COMP_STEP(A00, A01, A10, A11, B0, B1, B2, B3)                            \
  {                                                                              \
    v8s af0, af1;                                                                \
    PACK8(af0, A00, A01);                                                        \
    PACK8(af1, A10, A11);                                                        \
    v8s bf0 = __builtin_bit_cast(v8s, B0);                                       \
    v8s bf1 = __builtin_bit_cast(v8s, B1);                                       \
    v8s bf2 = __builtin_bit_cast(v8s, B2);                                       \
    v8s bf3 = __builtin_bit_cast(v8s, B3);                                       \
    acc00 = __builtin_amdgcn_mfma_f32_16x16x32_bf16(af0, bf0, acc00, 0, 0, 0);   \
    acc01 = __builtin_amdgcn_mfma_f32_16x16x32_bf16(af0, bf1, acc01, 0, 0, 0);   \
    acc02 = __builtin_amdgcn_mfma_f32_16x16x32_bf16(af0, bf2, acc02, 0, 0, 0);   \
    acc03 = __builtin_amdgcn_mfma_f32_16x16x32_bf16(af0, bf3, acc03, 0, 0, 0);   \
    acc10 = __builtin_amdgcn_mfma_f32_16x16x32_bf16(af1, bf0, acc10, 0, 0, 0);   \
    acc11 = __builtin_amdgcn_mfma_f32_16x16x32_bf16(af1, bf1, acc11, 0, 0, 0);   \
    acc12 = __builtin_amdgcn_mfma_f32_16x16x32_bf16(af1, bf2, acc12, 0, 0, 0);   \
    acc13 = __builtin_amdgcn_mfma_f32_16x16x32_bf16(af1, bf3, acc13, 0, 0, 0);   \
  }

#define STORE_FRAG(ACC, RF, UT)                                              \
  red[w][((RF)*16 + lhi * 4 + 0) * 64 + (UT)*16 + l15] = ACC.x;              \
  red[w][((RF)*16 + lhi * 4 + 1) * 64 + (UT)*16 + l15] = ACC.y;              \
  red[w][((RF)*16 + lhi * 4 + 2) * 64 + (UT)*16 + l15] = ACC.z;              \
  red[w][((RF)*16 + lhi * 4 + 3) * 64 + (UT)*16 + l15] = ACC.w;

__global__ __launch_bounds__(256, 1) void rgcn_main(const float* __restrict__ A,
                                                    const unsigned short* __restrict__ xwf,
                                                    float* __restrict__ out) {
  const int n0 = blockIdx.x * 32;   // 256 blocks x 32 rows
  const int w = threadIdx.x >> 6;   // wave = relation r
  const int l = threadIdx.x & 63;
  const int l15 = l & 15, lhi = l >> 4;
  // A-fragment: lane l -> row n0 + rf*16 + (l&15), k = m0 + 8*(l>>4) + j
  const float* a0 = A + ((size_t)w * 8192 + (size_t)(n0 + l15)) * 8192 + 8 * lhi;
  const float* a1 = a0 + (size_t)16 * 8192;
  const unsigned short* b0 = xwf + (size_t)w * 524288 + l * 8;

  v4f acc00 = {0.f, 0.f, 0.f, 0.f}, acc01 = {0.f, 0.f, 0.f, 0.f};
  v4f acc02 = {0.f, 0.f, 0.f, 0.f}, acc03 = {0.f, 0.f, 0.f, 0.f};
  v4f acc10 = {0.f, 0.f, 0.f, 0.f}, acc11 = {0.f, 0.f, 0.f, 0.f};
  v4f acc12 = {0.f, 0.f, 0.f, 0.f}, acc13 = {0.f, 0.f, 0.f, 0.f};

  v4f ca00, ca01, ca10, ca11;
  v4u cb0, cb1, cb2, cb3;
  v4f na00, na01, na10, na11;
  v4u nb0, nb1, nb2, nb3;

  LD_STEP(0, ca00, ca01, ca10, ca11, cb0, cb1, cb2, cb3);
  for (int it = 0; it < 254; it += 2) {
    LD_STEP(it + 1, na00, na01, na10, na11, nb0, nb1, nb2, nb3);
    COMP_STEP(ca00, ca01, ca10, ca11, cb0, cb1, cb2, cb3);
    LD_STEP(it + 2, ca00, ca01, ca10, ca11, cb0, cb1, cb2, cb3);
    COMP_STEP(na00, na01, na10, na11, nb0, nb1, nb2, nb3);
  }
  LD_STEP(255, na00, na01, na10, na11, nb0, nb1, nb2, nb3);
  COMP_STEP(ca00, ca01, ca10, ca11, cb0, cb1, cb2, cb3);
  COMP_STEP(na00, na01, na10, na11, nb0, nb1, nb2, nb3);

  // cross-relation reduction (D layout: col = l&15, row = 4*(l>>4)+reg)
  __shared__ float red[4][2048];
  STORE_FRAG(acc00, 0, 0)
  STORE_FRAG(acc01, 0, 1)
  STORE_FRAG(acc02, 0, 2)
  STORE_FRAG(acc03, 0, 3)
  STORE_FRAG(acc10, 1, 0)
  STORE_FRAG(acc11, 1, 1)
  STORE_FRAG(acc12, 1, 2)
  STORE_FRAG(acc13, 1, 3)
  __syncthreads();
  const int t = threadIdx.x;
#pragma unroll
  for (int p = 0; p < 8; ++p) {
    int i = t + 256 * p;
    float v = red[0][i] + red[1][i] + red[2][i] + red[3][i] + out[(size_t)n0 * 64 + i];
    out[(size_t)n0 * 64 + i] = fmaxf(v, 0.f);
  }
}

extern "C" void kernel_launch(void* const* d_in, const int* in_sizes, int n_in,
                              void* d_out, int out_size, void* d_ws, size_t ws_size,
                              hipStream_t stream) {
  const float* feat = (const float*)d_in[0];
  // d_in[1] = out_indices (int64) -- unused (final_layer=False returns all nodes)
  const float* adj = (const float*)d_in[2];
  const float* bases = (const float*)d_in[3];
  const float* coef = (const float*)d_in[4];
  const float* sk = (const float*)d_in[5];
  const float* bias = (const float*)d_in[6];
  float* out = (float*)d_out;

  // ws layout: [0, 4MB) xwf bf16 swizzled; [4MB, 4.25MB) W fp32
  unsigned short* xwf = (unsigned short*)d_ws;
  float* W = (float*)((char*)d_ws + (4u << 20));

  rgcn_wk<<<64, 256, 0, stream>>>(bases, coef, W);
  // selfout is staged in d_out; fully rewritten each call before being read.
  rgcn_prep<<<256, 256, 0, stream>>>(feat, W, sk, bias, xwf, out);
  rgcn_main<<<256, 256, 0, stream>>>(adj, xwf, out);

  (void)in_sizes;
  (void)n_in;
  (void)out_size;
  (void)ws_size;
}

// Round 2
// 219.530 us; speedup vs baseline: 1.1480x; 1.1480x over previous
//
#include <hip/hip_runtime.h>

// RGCN: out = relu( sum_r A_r @ (X W_r) + X Sk + bias )
// N=8192, F=U=64, R=4, B=20.  A (4,8192,8192) fp32 = 1.07 GB -> HBM-bound.
// Main kernel: barrier-free per-wave async global_load_lds pipeline, depth 2.

typedef float v4f __attribute__((ext_vector_type(4)));
typedef unsigned int v4u __attribute__((ext_vector_type(4)));
typedef short v8s __attribute__((ext_vector_type(8)));

__device__ __forceinline__ unsigned short f2bf(float f) {
  // round-to-nearest-even f32 -> bf16
  unsigned int u = __builtin_bit_cast(unsigned int, f);
  return (unsigned short)((u + 0x7fffu + ((u >> 16) & 1u)) >> 16);
}

__device__ __forceinline__ void gload16(const void* g, void* l) {
  __builtin_amdgcn_global_load_lds((const __attribute__((address_space(1))) void*)g,
                                   (__attribute__((address_space(3))) void*)l, 16, 0, 0);
}

// ---------------- kernel 0: W[r][f][u] = sum_k bases[f][u][k] * coef[r][k] ----
__global__ __launch_bounds__(256) void rgcn_wk(const float* __restrict__ bases,
                                               const float* __restrict__ coef,
                                               float* __restrict__ W) {
  int i = blockIdx.x * 256 + threadIdx.x;  // 64*256 = 16384 = R*F*U
  int r = i >> 12;
  int fu = i & 4095;
  float s = 0.f;
#pragma unroll
  for (int k = 0; k < 20; ++k) s += bases[fu * 20 + k] * coef[r * 20 + k];
  W[i] = s;
}

// ---------------- kernel 1: xw (bf16, swizzled to B-fragment layout) + selfout
// xwf layout: for K-step (r, m0=32*mb) and u-tile ut, lane l, elem j holds
//   xw[r][m0 + 8*(l>>4) + j][ut*16 + (l&15)]
//   at index ((r*256 + mb)*4 + ut)*512 + l*8 + j
__global__ __launch_bounds__(256) void rgcn_prep(const float* __restrict__ x,
                                                 const float* __restrict__ W,
                                                 const float* __restrict__ sk,
                                                 const float* __restrict__ bias,
                                                 unsigned short* __restrict__ xwf,
                                                 float* __restrict__ selfout) {
  __shared__ float lx[2048];            // 32 rows x 64 f
  __shared__ unsigned short lxw[8192];  // 4 rel x 2048 swizzled bf16
  const int t = threadIdx.x;
  const int blk = blockIdx.x;
  const int n0 = blk * 32;
  for (int i = t; i < 2048; i += 256) lx[i] = x[(size_t)n0 * 64 + i];
  __syncthreads();
  const int u = t & 63, rq = t >> 6;  // each thread: column u, rows rq*8..rq*8+7
  float acc[8][5];
#pragma unroll
  for (int p = 0; p < 8; ++p)
#pragma unroll
    for (int c = 0; c < 5; ++c) acc[p][c] = 0.f;
  const float* wu = W + u;   // W[r][f][u] = wu[r*4096 + f*64]
  const float* sku = sk + u;
#pragma unroll 4
  for (int f = 0; f < 64; ++f) {
    float w0 = wu[f * 64];
    float w1 = wu[4096 + f * 64];
    float w2 = wu[8192 + f * 64];
    float w3 = wu[12288 + f * 64];
    float w4 = sku[f * 64];
#pragma unroll
    for (int p = 0; p < 8; ++p) {
      float xv = lx[(rq * 8 + p) * 64 + f];
      acc[p][0] += xv * w0;
      acc[p][1] += xv * w1;
      acc[p][2] += xv * w2;
      acc[p][3] += xv * w3;
      acc[p][4] += xv * w4;
    }
  }
  const float bu = bias[u];
#pragma unroll
  for (int p = 0; p < 8; ++p) {
    int km = rq * 8 + p;  // local m index 0..31
    selfout[(size_t)(n0 + km) * 64 + u] = acc[p][4] + bu;
    int idx = (u >> 4) * 512 + ((km >> 3) * 16 + (u & 15)) * 8 + (km & 7);
#pragma unroll
    for (int r = 0; r < 4; ++r) lxw[r * 2048 + idx] = f2bf(acc[p][r]);
  }
  __syncthreads();
  const unsigned int* lsrc = (const unsigned int*)lxw;
  unsigned int* gdst = (unsigned int*)xwf;
  for (int i = t; i < 4096; i += 256) {  // 4 rel x 1024 dwords, coalesced
    int r = i >> 10, q = i & 1023;
    gdst[(size_t)(r * 256 + blk) * 1024 + q] = lsrc[i];
  }
}

// ---------------- kernel 2: out = relu( sum_r A_r @ xw_r + selfout ) --------
// LDS per (wave w, buf p): 8 KB at smem + (w*2+p)*8192:
//   A tile [32 rows][8 slots of 16B], slot swizzled: row r, slot c at r*8 + (c^(r&7))
//   B tile at +4096: linear, lane l's frag ut at 4096 + ut*1024 + l*16

#define PACK8(S, X0, X1)          \
  {                               \
    S[0] = (short)f2bf(X0.x);     \
    S[1] = (short)f2bf(X0.y);     \
    S[2] = (short)f2bf(X0.z);     \
    S[3] = (short)f2bf(X0.w);     \
    S[4] = (short)f2bf(X1.x);     \
    S[5] = (short)f2bf(X1.y);     \
    S[6] = (short)f2bf(X1.z);     \
    S[7] = (short)f2bf(X1.w);     \
  }

#define STAGE(P)                                          \
  {                                                       \
    char* stb = smem + (w * 2 + (P)) * 8192;              \
    gload16(aps0, stb);                                   \
    gload16(aps1, stb + 1024);                            \
    gload16(aps2, stb + 2048);                            \
    gload16(aps3, stb + 3072);                            \
    gload16(bpp, stb + 4096);                             \
    gload16(bpp + 512, stb + 5120);                       \
    gload16(bpp + 1024, stb + 6144);                      \
    gload16(bpp + 1536, stb + 7168);                      \
    aps0 += 32; aps1 += 32; aps2 += 32; aps3 += 32;       \
    bpp += 2048;                                          \
  }

#define STEP(P, VMN, DO_STAGE)                                             \
  {                                                                        \
    asm volatile("s_waitcnt vmcnt(" #VMN ")" ::: "memory");                \
    __builtin_amdgcn_sched_barrier(0);                                     \
    const char* sb = smem + (w * 2 + (P)) * 8192;                          \
    v4f a00 = *(const v4f*)(sb + ao00);                                    \
    v4f a01 = *(const v4f*)(sb + ao01);                                    \
    v4f a10 = *(const v4f*)(sb + ao10);                                    \
    v4f a11 = *(const v4f*)(sb + ao11);                                    \
    v4u b0 = *(const v4u*)(sb + bo);                                       \
    v4u b1 = *(const v4u*)(sb + bo + 1024);                                \
    v4u b2 = *(const v4u*)(sb + bo + 2048);                                \
    v4u b3 = *(const v4u*)(sb + bo + 3072);                                \
    asm volatile("s_waitcnt lgkmcnt(0)" ::: "memory");                     \
    __builtin_amdgcn_sched_barrier(0);                                     \
    if (DO_STAGE) STAGE(P)                                                 \
    v8s af0, af1;                                                          \
    PACK8(af0, a00, a01);                                                  \
    PACK8(af1, a10, a11);                                                  \
    v8s bf0 = __builtin_bit_cast(v8s, b0);                                 \
    v8s bf1 = __builtin_bit_cast(v8s, b1);                                 \
    v8s bf2 = __builtin_bit_cast(v8s, b2);                                 \
    v8s bf3 = __builtin_bit_cast(v8s, b3);                                 \
    acc00 = __builtin_amdgcn_mfma_f32_16x16x32_bf16(af0, bf0, acc00, 0, 0, 0); \
    acc01 = __builtin_amdgcn_mfma_f32_16x16x32_bf16(af0, bf1, acc01, 0, 0, 0); \
    acc02 = __builtin_amdgcn_mfma_f32_16x16x32_bf16(af0, bf2, acc02, 0, 0, 0); \
    acc03 = __builtin_amdgcn_mfma_f32_16x16x32_bf16(af0, bf3, acc03, 0, 0, 0); \
    acc10 = __builtin_amdgcn_mfma_f32_16x16x32_bf16(af1, bf0, acc10, 0, 0, 0); \
    acc11 = __builtin_amdgcn_mfma_f32_16x16x32_bf16(af1, bf1, acc11, 0, 0, 0); \
    acc12 = __builtin_amdgcn_mfma_f32_16x16x32_bf16(af1, bf2, acc12, 0, 0, 0); \
    acc13 = __builtin_amdgcn_mfma_f32_16x16x32_bf16(af1, bf3, acc13, 0, 0, 0); \
  }

#define STORE_FRAG(ACC, RF, UT)                                        \
  red[w][((RF)*16 + lhi * 4 + 0) * 64 + (UT)*16 + l15] = ACC.x;        \
  red[w][((RF)*16 + lhi * 4 + 1) * 64 + (UT)*16 + l15] = ACC.y;        \
  red[w][((RF)*16 + lhi * 4 + 2) * 64 + (UT)*16 + l15] = ACC.z;        \
  red[w][((RF)*16 + lhi * 4 + 3) * 64 + (UT)*16 + l15] = ACC.w;

__global__ __launch_bounds__(256, 1) void rgcn_main(const float* __restrict__ A,
                                                    const unsigned short* __restrict__ xwf,
                                                    float* __restrict__ out) {
  __shared__ __align__(16) char smem[65536];  // 4 waves x 2 bufs x 8KB; reused for red
  const int tid = threadIdx.x;
  const int n0 = blockIdx.x * 32;
  const int w = tid >> 6;  // wave = relation
  const int l = tid & 63;
  const int l15 = l & 15, lhi = l >> 4;

  // A staging sources (pre-swizzled): instr j covers rows j*8+(l>>3),
  // slot (l&7)^(l>>3); lands at LDS slot j*64+l (linear, 16B units).
  const float* aps0 = A + ((size_t)w * 8192 + (size_t)(n0 + 0 + (l >> 3))) * 8192 + (((l & 7) ^ (l >> 3)) << 2);
  const float* aps1 = aps0 + (size_t)8 * 8192;
  const float* aps2 = aps0 + (size_t)16 * 8192;
  const float* aps3 = aps0 + (size_t)24 * 8192;
  // B staging source: lane-linear within (r, step, ut)
  const unsigned short* bpp = xwf + (size_t)(w * 256) * 2048 + (size_t)l * 8;

  // ds_read offsets: A frag rf, half b: row=rf*16+l15, slot=(2*lhi+b)^(row&7)
  const int ao00 = ((0 * 16 + l15) * 8 + ((lhi * 2 + 0) ^ (l15 & 7))) * 16;
  const int ao01 = ((0 * 16 + l15) * 8 + ((lhi * 2 + 1) ^ (l15 & 7))) * 16;
  const int ao10 = ((1 * 16 + l15) * 8 + ((lhi * 2 + 0) ^ (l15 & 7))) * 16;
  const int ao11 = ((1 * 16 + l15) * 8 + ((lhi * 2 + 1) ^ (l15 & 7))) * 16;
  const int bo = 4096 + l * 16;

  v4f acc00 = {0.f, 0.f, 0.f, 0.f}, acc01 = {0.f, 0.f, 0.f, 0.f};
  v4f acc02 = {0.f, 0.f, 0.f, 0.f}, acc03 = {0.f, 0.f, 0.f, 0.f};
  v4f acc10 = {0.f, 0.f, 0.f, 0.f}, acc11 = {0.f, 0.f, 0.f, 0.f};
  v4f acc12 = {0.f, 0.f, 0.f, 0.f}, acc13 = {0.f, 0.f, 0.f, 0.f};

  STAGE(0)  // step 0
  STAGE(1)  // step 1
  for (int t = 0; t < 127; ++t) {
    STEP(0, 8, 1)  // compute step 2t,   stage step 2t+2
    STEP(1, 8, 1)  // compute step 2t+1, stage step 2t+3
  }
  STEP(0, 8, 0)  // step 254
  STEP(1, 0, 0)  // step 255

  // cross-relation reduction (D layout: col = l&15, row = 4*(l>>4)+reg)
  __syncthreads();
  float(*red)[2048] = (float(*)[2048])smem;
  STORE_FRAG(acc00, 0, 0)
  STORE_FRAG(acc01, 0, 1)
  STORE_FRAG(acc02, 0, 2)
  STORE_FRAG(acc03, 0, 3)
  STORE_FRAG(acc10, 1, 0)
  STORE_FRAG(acc11, 1, 1)
  STORE_FRAG(acc12, 1, 2)
  STORE_FRAG(acc13, 1, 3)
  __syncthreads();
#pragma unroll
  for (int p = 0; p < 8; ++p) {
    int i = tid + 256 * p;
    float v = red[0][i] + red[1][i] + red[2][i] + red[3][i] + out[(size_t)n0 * 64 + i];
    out[(size_t)n0 * 64 + i] = fmaxf(v, 0.f);
  }
}

extern "C" void kernel_launch(void* const* d_in, const int* in_sizes, int n_in,
                              void* d_out, int out_size, void* d_ws, size_t ws_size,
                              hipStream_t stream) {
  const float* feat = (const float*)d_in[0];
  // d_in[1] = out_indices (int64) -- unused (final_layer=False returns all nodes)
  const float* adj = (const float*)d_in[2];
  const float* bases = (const float*)d_in[3];
  const float* coef = (const float*)d_in[4];
  const float* sk = (const float*)d_in[5];
  const float* bias = (const float*)d_in[6];
  float* out = (float*)d_out;

  // ws layout: [0, 4MB) xwf bf16 swizzled; [4MB, 4.25MB) W fp32
  unsigned short* xwf = (unsigned short*)d_ws;
  float* W = (float*)((char*)d_ws + (4u << 20));

  rgcn_wk<<<64, 256, 0, stream>>>(bases, coef, W);
  // selfout is staged in d_out; fully rewritten each call before being read.
  rgcn_prep<<<256, 256, 0, stream>>>(feat, W, sk, bias, xwf, out);
  rgcn_main<<<256, 256, 0, stream>>>(adj, xwf, out);

  (void)in_sizes;
  (void)n_in;
  (void)out_size;
  (void)ws_size;
}